// Round 2
// baseline (351.006 us; speedup 1.0000x reference)
//
#include <hip/hip_runtime.h>
#include <math.h>

typedef unsigned int u32;
typedef unsigned long long u64;

#define HW    30720     // 96*320
#define W_    320
#define H_    96
#define B_    16
#define KTOP  100
#define NIMG  192       // 16*3 (hm) + 16*9 (hm_hp)
#define CAP   6144      // per-row candidate capacity (~3400 expected survivors)
#define BPR   120       // blocks per row-image in kernel 1 (HW/256)

// ---------------------------------------------------------------------------
// Kernel 0: zero the per-row candidate counters (ws is poisoned every launch).
// ---------------------------------------------------------------------------
__global__ __launch_bounds__(256) void init_kernel(u32* __restrict__ rowcnt) {
    int t = threadIdx.x;
    if (t < NIMG) rowcnt[t] = 0;
}

// ---------------------------------------------------------------------------
// Kernel 1: fused sigmoid + 3x3 NMS + survivor compaction.
// Each block covers 256 consecutive pixels of one (b,c) image. Survivors
// (3x3 local maxima) get key = float bits of sigmoid(center) (monotone,
// positive, never 0) packed with ~pixel_index, compacted block-locally in
// LDS, then appended to the row's global candidate buffer with ONE global
// atomicAdd per block.
// ---------------------------------------------------------------------------
__global__ __launch_bounds__(256) void nms_compact_kernel(
    const float* __restrict__ hm, const float* __restrict__ hm_hp,
    u64* __restrict__ rowbuf, u32* __restrict__ rowcnt)
{
    const int blk = blockIdx.x;
    const int img = blk / BPR;
    const int pix = (blk - img * BPR) * 256 + threadIdx.x;
    const int tid = threadIdx.x;
    const float* base = (img < 48) ? (hm + (size_t)img * HW)
                                   : (hm_hp + (size_t)(img - 48) * HW);
    int y = pix / W_;
    int x = pix - y * W_;
    float c = base[pix];
    float m = c;
    int y0 = (y > 0) ? y - 1 : 0, y1 = (y < H_ - 1) ? y + 1 : H_ - 1;
    int x0 = (x > 0) ? x - 1 : 0, x1 = (x < W_ - 1) ? x + 1 : W_ - 1;
    for (int yy = y0; yy <= y1; ++yy)
        for (int xx = x0; xx <= x1; ++xx)
            m = fmaxf(m, base[yy * W_ + xx]);

    __shared__ u32 lcnt, gbase;
    __shared__ u64 lc[256];
    if (tid == 0) lcnt = 0;
    __syncthreads();

    if (c == m) {
        float s = 1.0f / (1.0f + expf(-c));
        u32 key = __float_as_uint(s);           // monotone bits, always > 0
        u32 p = atomicAdd(&lcnt, 1u);
        lc[p] = ((u64)key << 32) | (u32)(~(u32)pix);
    }
    __syncthreads();
    if (tid == 0) gbase = (lcnt > 0) ? atomicAdd(&rowcnt[img], lcnt) : 0u;
    __syncthreads();
    u32 n = lcnt;
    if (tid < n) {
        u32 p = gbase + tid;
        if (p < CAP) rowbuf[(size_t)img * CAP + p] = lc[tid];
    }
}

// ---------------------------------------------------------------------------
// Kernel 2: exact per-row top-100 (lax.top_k semantics: value desc, idx asc)
// over the compacted candidate list. Candidates are loaded once into LDS;
// two-round 12-bit radix select finds a 24-bit-prefix cut with >= 100
// qualifying keys; qualifiers are compacted and bitonic-sorted as packed
// (key, ~idx) u64s. Selection is order-independent, so the nondeterministic
// compaction order from kernel 1 cannot affect the result.
// ---------------------------------------------------------------------------
__global__ __launch_bounds__(256) void select_kernel(
    const u64* __restrict__ rowbuf, const u32* __restrict__ rowcnt,
    u32* __restrict__ tkKey, u32* __restrict__ tkIdx)
{
    const int row = blockIdx.x;
    const int tid = threadIdx.x;

    __shared__ u64 cand[CAP];       // 48 KB
    __shared__ u32 hist[4096];      // 16 KB
    __shared__ u64 cand2[2048];     // 16 KB
    __shared__ u32 chunkv[256];
    __shared__ u32 sel[3];          // b1, G1, b2
    __shared__ u32 cnt2;

    u32 n = rowcnt[row]; if (n > CAP) n = CAP;
    const u64* src = rowbuf + (size_t)row * CAP;
    for (u32 i = tid; i < n; i += 256) cand[i] = src[i];

    // ---- round 1: histogram of key[31:20] ----
    for (int i = tid; i < 4096; i += 256) hist[i] = 0;
    __syncthreads();
    for (u32 i = tid; i < n; i += 256)
        atomicAdd(&hist[(u32)(cand[i] >> 52)], 1u);   // key>>20 == packed>>52
    __syncthreads();
    { u32 s = 0; int c0 = tid * 16;
      for (int q = 0; q < 16; ++q) s += hist[c0 + q];
      chunkv[tid] = s; }
    __syncthreads();
    if (tid == 0) {
        u32 run = 0; u32 b1 = 0, G1 = 0;
        for (int c = 255; c >= 0; --c) {
            u32 s = chunkv[c];
            if (run + s >= KTOP) {
                for (int bin = c * 16 + 15; bin >= c * 16; --bin) {
                    u32 h = hist[bin];
                    if (run + h >= KTOP) { b1 = (u32)bin; G1 = run; break; }
                    run += h;
                }
                break;
            }
            run += s;
        }
        sel[0] = b1; sel[1] = G1;
    }
    __syncthreads();
    const u32 b1 = sel[0], G1 = sel[1];

    // ---- round 2: refine within bin b1 on key[19:8] ----
    for (int i = tid; i < 4096; i += 256) hist[i] = 0;
    __syncthreads();
    for (u32 i = tid; i < n; i += 256) {
        u32 k = (u32)(cand[i] >> 32);
        if ((k >> 20) == b1) atomicAdd(&hist[(k >> 8) & 0xFFFu], 1u);
    }
    __syncthreads();
    { u32 s = 0; int c0 = tid * 16;
      for (int q = 0; q < 16; ++q) s += hist[c0 + q];
      chunkv[tid] = s; }
    __syncthreads();
    if (tid == 0) {
        u32 K2 = KTOP - G1;   // >= 1
        u32 run = 0; u32 b2 = 0;
        for (int c = 255; c >= 0; --c) {
            u32 s = chunkv[c];
            if (run + s >= K2) {
                for (int bin = c * 16 + 15; bin >= c * 16; --bin) {
                    u32 h = hist[bin];
                    if (run + h >= K2) { b2 = (u32)bin; break; }
                    run += h;
                }
                break;
            }
            run += s;
        }
        sel[2] = b2;
        cnt2 = 0;
    }
    __syncthreads();
    const u32 cut24 = (b1 << 12) | sel[2];

    // ---- compact qualifiers (24-bit prefix >= cut) ----
    for (u32 i = tid; i < n; i += 256) {
        u64 v = cand[i];
        if ((u32)(v >> 40) >= cut24) {            // key>>8 == packed>>40
            u32 p = atomicAdd(&cnt2, 1u);
            if (p < 2048) cand2[p] = v;
        }
    }
    __syncthreads();
    u32 m = cnt2; if (m > 2048) m = 2048;
    u32 npow = 128; while (npow < m) npow <<= 1;
    for (u32 i = m + tid; i < npow; i += 256) cand2[i] = 0ull;
    __syncthreads();

    // ---- bitonic sort descending (key desc, idx asc via ~idx) ----
    for (u32 ks = 2; ks <= npow; ks <<= 1) {
        for (u32 j = ks >> 1; j > 0; j >>= 1) {
            for (u32 i = tid; i < npow; i += 256) {
                u32 ix = i ^ j;
                if (ix > i) {
                    u64 a = cand2[i], b = cand2[ix];
                    bool sw = ((i & ks) == 0) ? (a < b) : (a > b);
                    if (sw) { cand2[i] = b; cand2[ix] = a; }
                }
            }
            __syncthreads();
        }
    }
    if (tid < KTOP) {
        u64 v = cand2[tid];
        tkKey[row * KTOP + tid] = (u32)(v >> 32);
        tkIdx[row * KTOP + tid] = ~(u32)v;
    }
}

// ---------------------------------------------------------------------------
// Kernel 3: per-batch decode (unchanged from validated round-1 version).
// ---------------------------------------------------------------------------
__global__ __launch_bounds__(256) void decode_kernel(
    const u32* __restrict__ tkKey, const u32* __restrict__ tkIdx,
    const float* __restrict__ wh,   const float* __restrict__ hps,
    const float* __restrict__ dimp, const float* __restrict__ rot,
    const float* __restrict__ prob, const float* __restrict__ reg,
    const float* __restrict__ hpo,  float* __restrict__ det)
{
    const int b = blockIdx.x;
    const int tid = threadIdx.x;

    __shared__ u64 arr[512];
    __shared__ float la[KTOP], ta[KTOP], ra[KTOP], ba2[KTOP];
    __shared__ float kx[9][KTOP], ky[9][KTOP];
    __shared__ float hsv[9][KTOP], hxv[9][KTOP], hyv[9][KTOP];

    // ---- second-stage topk over the 3 channels' 100 each ----
    for (int i = tid; i < 512; i += 256) {
        u64 v = 0ull;
        if (i < 300) {
            int c = i / 100, r = i - c * 100;
            u32 key = tkKey[(b * 3 + c) * KTOP + r];
            v = ((u64)key << 32) | (u32)(~(u32)i);
        }
        arr[i] = v;
    }
    __syncthreads();
    for (u32 ks = 2; ks <= 512; ks <<= 1) {
        for (u32 j = ks >> 1; j > 0; j >>= 1) {
            for (u32 i = tid; i < 512; i += 256) {
                u32 ix = i ^ j;
                if (ix > i) {
                    u64 a = arr[i], bb = arr[ix];
                    bool sw = ((i & ks) == 0) ? (a < bb) : (a > bb);
                    if (sw) { arr[i] = bb; arr[ix] = a; }
                }
            }
            __syncthreads();
        }
    }

    // ---- hm_hp candidates: score/x/y with offset + validity masking ----
    for (int t2 = tid; t2 < 900; t2 += 256) {
        int j = t2 / 100, r = t2 - j * 100;
        int row = 48 + b * 9 + j;
        u32 key = tkKey[row * KTOP + r];
        u32 idx = tkIdx[row * KTOP + r];
        if (idx > HW - 1) idx = HW - 1;          // safety (pad entries)
        float s = __uint_as_float(key);
        int yy = (int)idx / W_, xx = (int)idx - yy * W_;
        float hx = (float)xx + hpo[((size_t)b * 2 + 0) * HW + idx];
        float hy = (float)yy + hpo[((size_t)b * 2 + 1) * HW + idx];
        bool valid = s > 0.1f;
        hsv[j][r] = valid ? s : -1.0f;
        hxv[j][r] = valid ? hx : -10000.0f;
        hyv[j][r] = valid ? hy : -10000.0f;
    }

    // ---- per-detection gathers + direct writes of non-kps fields ----
    if (tid < KTOP) {
        int k = tid;
        u64 v = arr[k];
        u32 pos = ~(u32)v;
        if (pos > 299u) pos = 299u;              // safety (pad entries)
        u32 key = (u32)(v >> 32);
        int c = (int)pos / 100, r = (int)pos - c * 100;
        u32 sid = tkIdx[(b * 3 + c) * KTOP + r];
        if (sid > HW - 1) sid = HW - 1;          // safety
        float score = __uint_as_float(key);
        int yy = (int)sid / W_, xx = (int)sid - yy * W_;
        float xs0 = (float)xx, ys0 = (float)yy;
        float r0 = reg[((size_t)b * 2 + 0) * HW + sid];
        float r1 = reg[((size_t)b * 2 + 1) * HW + sid];
        float xsv = xs0 + r0, ysv = ys0 + r1;
        float w0 = wh[((size_t)b * 2 + 0) * HW + sid];
        float w1 = wh[((size_t)b * 2 + 1) * HW + sid];
        float l  = xsv - w0 * 0.5f;
        float t  = ysv - w1 * 0.5f;
        float rr = xsv + w0 * 0.5f;
        float bb = ysv + w1 * 0.5f;
        la[k] = l; ta[k] = t; ra[k] = rr; ba2[k] = bb;

        float* o = det + ((size_t)b * KTOP + k) * 45;
        o[0] = l * 4.0f; o[1] = t * 4.0f; o[2] = rr * 4.0f; o[3] = bb * 4.0f;
        o[4] = score;
        #pragma unroll
        for (int q = 0; q < 3; ++q)
            o[23 + q] = dimp[((size_t)b * 3 + q) * HW + sid];
        #pragma unroll
        for (int q = 0; q < 8; ++q)
            o[35 + q] = rot[((size_t)b * 8 + q) * HW + sid];
        o[43] = prob[(size_t)b * HW + sid];
        o[44] = (float)c;
        #pragma unroll
        for (int j = 0; j < 9; ++j) {
            kx[j][k] = hps[((size_t)b * 18 + 2 * j)     * HW + sid] + xs0;
            ky[j][k] = hps[((size_t)b * 18 + 2 * j + 1) * HW + sid] + ys0;
        }
    }
    __syncthreads();

    // ---- min-distance matching (argmin first-wins) + kps compose ----
    for (int p = tid; p < 900; p += 256) {
        int j = p / 100, k = p - j * 100;
        float qx = kx[j][k], qy = ky[j][k];
        float best = INFINITY; int bi = 0;
        for (int m = 0; m < 100; ++m) {
            float dx = qx - hxv[j][m];
            float dy = qy - hyv[j][m];
            float d2 = __fadd_rn(__fmul_rn(dx, dx), __fmul_rn(dy, dy));
            float d = __fsqrt_rn(d2);
            if (d < best) { best = d; bi = m; }
        }
        float ss = hsv[j][bi], hx = hxv[j][bi], hy = hyv[j][bi];
        float l = la[k], t = ta[k], rr = ra[k], bb = ba2[k];
        float th = __fmul_rn(fmaxf(__fsub_rn(bb, t), __fsub_rn(rr, l)), 0.3f);
        bool invalid = (hx < l) | (hx > rr) | (hy < t) | (hy > bb) |
                       (ss < 0.1f) | (best > th);
        float ox = invalid ? kx[j][k] : hx;
        float oy = invalid ? ky[j][k] : hy;
        float* o = det + ((size_t)b * KTOP + k) * 45;
        o[5 + 2 * j] = ox * 4.0f;
        o[6 + 2 * j] = oy * 4.0f;
        o[26 + j]    = ss;
    }
}

// ---------------------------------------------------------------------------
extern "C" void kernel_launch(void* const* d_in, const int* in_sizes, int n_in,
                              void* d_out, int out_size, void* d_ws, size_t ws_size,
                              hipStream_t stream) {
    const float* hm    = (const float*)d_in[0];
    const float* wh    = (const float*)d_in[1];
    const float* hps   = (const float*)d_in[2];
    const float* dimp  = (const float*)d_in[3];
    const float* rot   = (const float*)d_in[4];
    const float* prob  = (const float*)d_in[5];
    const float* reg   = (const float*)d_in[6];
    const float* hm_hp = (const float*)d_in[7];
    const float* hpo   = (const float*)d_in[8];
    float* det = (float*)d_out;

    u64* rowbuf = (u64*)d_ws;                         // 192*6144*8 = 9.4 MB
    u32* rowcnt = (u32*)(rowbuf + (size_t)NIMG * CAP);// 192 (pad 256)
    u32* tkKey  = rowcnt + 256;                       // 192*100
    u32* tkIdx  = tkKey + NIMG * KTOP;                // 192*100

    init_kernel<<<1, 256, 0, stream>>>(rowcnt);
    nms_compact_kernel<<<NIMG * BPR, 256, 0, stream>>>(hm, hm_hp, rowbuf, rowcnt);
    select_kernel<<<NIMG, 256, 0, stream>>>(rowbuf, rowcnt, tkKey, tkIdx);
    decode_kernel<<<B_, 256, 0, stream>>>(tkKey, tkIdx, wh, hps, dimp, rot,
                                          prob, reg, hpo, det);
}

// Round 3
// 186.486 us; speedup vs baseline: 1.8822x; 1.8822x over previous
//
#include <hip/hip_runtime.h>
#include <math.h>

typedef unsigned int u32;
typedef unsigned long long u64;

#define HW    30720     // 96*320
#define W_    320
#define H_    96
#define B_    16
#define KTOP  100
#define NIMG  192       // 16*3 (hm) + 16*9 (hm_hp)
#define NTHR  1024
#define SCAP  4096      // survivor capacity (expected ~3460, 11+ sigma margin)

// ---------------------------------------------------------------------------
// Fused kernel: one block per (b,c) image.
//  1. Stage full 96x320 image in LDS (float4 coalesced).
//  2. 3x3 NMS from LDS (shared column-max, clamped borders) -> survivor idxs.
//  3. Survivors: sigmoid key (fp32, same expr as validated rounds), packed
//     (key<<32)|~idx u64 written over the (no-longer-needed) image LDS.
//  4. Exact top-100 (lax.top_k semantics: value desc, idx asc): two-round
//     12-bit radix select with PARALLEL suffix-scan cut finding, compact,
//     bitonic sort, emit 100 (key, idx) pairs.
// ---------------------------------------------------------------------------
__global__ __launch_bounds__(NTHR) void fused_nms_select_kernel(
    const float* __restrict__ hm, const float* __restrict__ hm_hp,
    u32* __restrict__ tkKey, u32* __restrict__ tkIdx)
{
    const int row = blockIdx.x;
    const int tid = threadIdx.x;

    __shared__ __align__(16) float img[HW];   // 120 KB; later reused as u64 cand area
    __shared__ u32 cidx[SCAP];                // 16 KB; survivor idxs, later hist[4096]
    __shared__ u32 chunkv[256];
    __shared__ u32 sel[2];                    // b1|... , G1
    __shared__ u32 selb2;
    __shared__ u32 cnt, cnt2;

    u64* imgU64 = (u64*)img;                  // [0..4095]: candidates
    u64* cand2  = imgU64 + SCAP;              // [4096..6143]: qualifiers (16 KB)
    u32* hist   = cidx;                       // alias after survivors consumed

    if (tid == 0) { cnt = 0; cnt2 = 0; }

    // ---- phase 1: stage image ----
    const float4* src4 = (const float4*)((row < 48)
        ? (hm + (size_t)row * HW) : (hm_hp + (size_t)(row - 48) * HW));
    float4* img4 = (float4*)img;
    #pragma unroll
    for (int j = 0; j < HW / 4 / NTHR + 1; ++j) {
        int i = tid + j * NTHR;
        if (i < HW / 4) img4[i] = src4[i];
    }
    __syncthreads();

    // ---- phase 2: 3x3 NMS from LDS, quad at a time ----
    for (int q = tid; q < HW / 4; q += NTHR) {
        int pix0 = q * 4;
        int y = pix0 / W_;
        int x0 = pix0 - y * W_;
        int ym = (y > 0 ? y - 1 : 0) * W_;
        int yc = y * W_;
        int yp = (y < H_ - 1 ? y + 1 : H_ - 1) * W_;
        float cm[6];
        #pragma unroll
        for (int c = 0; c < 6; ++c) {
            int xc = x0 - 1 + c;
            xc = (xc < 0) ? 0 : (xc > W_ - 1 ? W_ - 1 : xc);
            cm[c] = fmaxf(fmaxf(img[ym + xc], img[yc + xc]), img[yp + xc]);
        }
        #pragma unroll
        for (int j = 0; j < 4; ++j) {
            float cen = img[yc + x0 + j];
            float m = fmaxf(fmaxf(cm[j], cm[j + 1]), cm[j + 2]);
            if (cen == m) {
                u32 p = atomicAdd(&cnt, 1u);
                if (p < SCAP) cidx[p] = (u32)(pix0 + j);
            }
        }
    }
    __syncthreads();

    u32 n = cnt; if (n > SCAP) n = SCAP;

    // ---- phase 3a: read raw values + sigmoid into regs ----
    u64 kv[4];
    #pragma unroll
    for (int j = 0; j < 4; ++j) {
        u32 i = tid + j * NTHR;
        if (i < n) {
            u32 pix = cidx[i];
            float c = img[pix];
            float s = 1.0f / (1.0f + expf(-c));
            kv[j] = ((u64)__float_as_uint(s) << 32) | (u32)(~pix);
        } else kv[j] = 0ull;
    }
    __syncthreads();
    // ---- phase 3b: write candidates over img; zero hist (= cidx alias is
    //      still needed? no: cidx fully consumed into kv above) ----
    #pragma unroll
    for (int j = 0; j < 4; ++j) {
        u32 i = tid + j * NTHR;
        if (i < n) imgU64[i] = kv[j];
    }
    for (int i = tid; i < 4096; i += NTHR) hist[i] = 0;
    __syncthreads();

    // ---- round 1: histogram key[31:20] ----
    for (u32 i = tid; i < n; i += NTHR)
        atomicAdd(&hist[(u32)(imgU64[i] >> 52)], 1u);
    __syncthreads();
    if (tid < 256) {
        u32 s = 0; int c0 = tid * 16;
        #pragma unroll
        for (int q = 0; q < 16; ++q) s += hist[c0 + q];
        chunkv[tid] = s;
    }
    __syncthreads();
    // parallel suffix scan: chunkv[c] = sum_{j>=c} chunkv[j]
    for (int d = 1; d < 256; d <<= 1) {
        u32 t = 0;
        if (tid < 256 - d) t = chunkv[tid + d];
        __syncthreads();
        if (tid < 256) chunkv[tid] += t;
        __syncthreads();
    }
    if (tid < 256) {
        u32 Sc = chunkv[tid];
        u32 Sn = (tid == 255) ? 0u : chunkv[tid + 1];
        if (Sc >= KTOP && Sn < KTOP) {      // exactly one thread
            u32 run = Sn, b1 = 0, G1 = 0;
            for (int bin = tid * 16 + 15; bin >= tid * 16; --bin) {
                u32 h = hist[bin];
                if (run + h >= KTOP) { b1 = (u32)bin; G1 = run; break; }
                run += h;
            }
            sel[0] = b1; sel[1] = G1;
        }
    }
    __syncthreads();
    const u32 b1 = sel[0], G1 = sel[1];

    // ---- round 2: refine on key[19:8] within bin b1 ----
    for (int i = tid; i < 4096; i += NTHR) hist[i] = 0;
    __syncthreads();
    for (u32 i = tid; i < n; i += NTHR) {
        u32 k = (u32)(imgU64[i] >> 32);
        if ((k >> 20) == b1) atomicAdd(&hist[(k >> 8) & 0xFFFu], 1u);
    }
    __syncthreads();
    if (tid < 256) {
        u32 s = 0; int c0 = tid * 16;
        #pragma unroll
        for (int q = 0; q < 16; ++q) s += hist[c0 + q];
        chunkv[tid] = s;
    }
    __syncthreads();
    for (int d = 1; d < 256; d <<= 1) {
        u32 t = 0;
        if (tid < 256 - d) t = chunkv[tid + d];
        __syncthreads();
        if (tid < 256) chunkv[tid] += t;
        __syncthreads();
    }
    {
        const u32 K2 = KTOP - G1;           // >= 1
        if (tid < 256) {
            u32 Sc = chunkv[tid];
            u32 Sn = (tid == 255) ? 0u : chunkv[tid + 1];
            if (Sc >= K2 && Sn < K2) {
                u32 run = Sn, b2 = 0;
                for (int bin = tid * 16 + 15; bin >= tid * 16; --bin) {
                    u32 h = hist[bin];
                    if (run + h >= K2) { b2 = (u32)bin; break; }
                    run += h;
                }
                selb2 = b2;
            }
        }
    }
    __syncthreads();
    const u32 cut24 = (b1 << 12) | selb2;

    // ---- compact qualifiers (24-bit prefix >= cut) ----
    for (u32 i = tid; i < n; i += NTHR) {
        u64 v = imgU64[i];
        if ((u32)(v >> 40) >= cut24) {
            u32 p = atomicAdd(&cnt2, 1u);
            if (p < 2048) cand2[p] = v;
        }
    }
    __syncthreads();
    u32 m = cnt2; if (m > 2048) m = 2048;
    u32 npow = 128; while (npow < m) npow <<= 1;
    for (u32 i = m + tid; i < npow; i += NTHR) cand2[i] = 0ull;
    __syncthreads();

    // ---- bitonic sort descending (key desc, idx asc via ~idx) ----
    for (u32 ks = 2; ks <= npow; ks <<= 1) {
        for (u32 j = ks >> 1; j > 0; j >>= 1) {
            for (u32 i = tid; i < npow; i += NTHR) {
                u32 ix = i ^ j;
                if (ix > i) {
                    u64 a = cand2[i], b = cand2[ix];
                    bool sw = ((i & ks) == 0) ? (a < b) : (a > b);
                    if (sw) { cand2[i] = b; cand2[ix] = a; }
                }
            }
            __syncthreads();
        }
    }
    if (tid < KTOP) {
        u64 v = cand2[tid];
        tkKey[row * KTOP + tid] = (u32)(v >> 32);
        tkIdx[row * KTOP + tid] = ~(u32)v;
    }
}

// ---------------------------------------------------------------------------
// Decode kernel (unchanged — validated absmax 0.0 in rounds 1 & 2).
// ---------------------------------------------------------------------------
__global__ __launch_bounds__(256) void decode_kernel(
    const u32* __restrict__ tkKey, const u32* __restrict__ tkIdx,
    const float* __restrict__ wh,   const float* __restrict__ hps,
    const float* __restrict__ dimp, const float* __restrict__ rot,
    const float* __restrict__ prob, const float* __restrict__ reg,
    const float* __restrict__ hpo,  float* __restrict__ det)
{
    const int b = blockIdx.x;
    const int tid = threadIdx.x;

    __shared__ u64 arr[512];
    __shared__ float la[KTOP], ta[KTOP], ra[KTOP], ba2[KTOP];
    __shared__ float kx[9][KTOP], ky[9][KTOP];
    __shared__ float hsv[9][KTOP], hxv[9][KTOP], hyv[9][KTOP];

    // ---- second-stage topk over the 3 channels' 100 each ----
    for (int i = tid; i < 512; i += 256) {
        u64 v = 0ull;
        if (i < 300) {
            int c = i / 100, r = i - c * 100;
            u32 key = tkKey[(b * 3 + c) * KTOP + r];
            v = ((u64)key << 32) | (u32)(~(u32)i);
        }
        arr[i] = v;
    }
    __syncthreads();
    for (u32 ks = 2; ks <= 512; ks <<= 1) {
        for (u32 j = ks >> 1; j > 0; j >>= 1) {
            for (u32 i = tid; i < 512; i += 256) {
                u32 ix = i ^ j;
                if (ix > i) {
                    u64 a = arr[i], bb = arr[ix];
                    bool sw = ((i & ks) == 0) ? (a < bb) : (a > bb);
                    if (sw) { arr[i] = bb; arr[ix] = a; }
                }
            }
            __syncthreads();
        }
    }

    // ---- hm_hp candidates: score/x/y with offset + validity masking ----
    for (int t2 = tid; t2 < 900; t2 += 256) {
        int j = t2 / 100, r = t2 - j * 100;
        int row = 48 + b * 9 + j;
        u32 key = tkKey[row * KTOP + r];
        u32 idx = tkIdx[row * KTOP + r];
        if (idx > HW - 1) idx = HW - 1;          // safety (pad entries)
        float s = __uint_as_float(key);
        int yy = (int)idx / W_, xx = (int)idx - yy * W_;
        float hx = (float)xx + hpo[((size_t)b * 2 + 0) * HW + idx];
        float hy = (float)yy + hpo[((size_t)b * 2 + 1) * HW + idx];
        bool valid = s > 0.1f;
        hsv[j][r] = valid ? s : -1.0f;
        hxv[j][r] = valid ? hx : -10000.0f;
        hyv[j][r] = valid ? hy : -10000.0f;
    }

    // ---- per-detection gathers + direct writes of non-kps fields ----
    if (tid < KTOP) {
        int k = tid;
        u64 v = arr[k];
        u32 pos = ~(u32)v;
        if (pos > 299u) pos = 299u;              // safety (pad entries)
        u32 key = (u32)(v >> 32);
        int c = (int)pos / 100, r = (int)pos - c * 100;
        u32 sid = tkIdx[(b * 3 + c) * KTOP + r];
        if (sid > HW - 1) sid = HW - 1;          // safety
        float score = __uint_as_float(key);
        int yy = (int)sid / W_, xx = (int)sid - yy * W_;
        float xs0 = (float)xx, ys0 = (float)yy;
        float r0 = reg[((size_t)b * 2 + 0) * HW + sid];
        float r1 = reg[((size_t)b * 2 + 1) * HW + sid];
        float xsv = xs0 + r0, ysv = ys0 + r1;
        float w0 = wh[((size_t)b * 2 + 0) * HW + sid];
        float w1 = wh[((size_t)b * 2 + 1) * HW + sid];
        float l  = xsv - w0 * 0.5f;
        float t  = ysv - w1 * 0.5f;
        float rr = xsv + w0 * 0.5f;
        float bb = ysv + w1 * 0.5f;
        la[k] = l; ta[k] = t; ra[k] = rr; ba2[k] = bb;

        float* o = det + ((size_t)b * KTOP + k) * 45;
        o[0] = l * 4.0f; o[1] = t * 4.0f; o[2] = rr * 4.0f; o[3] = bb * 4.0f;
        o[4] = score;
        #pragma unroll
        for (int q = 0; q < 3; ++q)
            o[23 + q] = dimp[((size_t)b * 3 + q) * HW + sid];
        #pragma unroll
        for (int q = 0; q < 8; ++q)
            o[35 + q] = rot[((size_t)b * 8 + q) * HW + sid];
        o[43] = prob[(size_t)b * HW + sid];
        o[44] = (float)c;
        #pragma unroll
        for (int j = 0; j < 9; ++j) {
            kx[j][k] = hps[((size_t)b * 18 + 2 * j)     * HW + sid] + xs0;
            ky[j][k] = hps[((size_t)b * 18 + 2 * j + 1) * HW + sid] + ys0;
        }
    }
    __syncthreads();

    // ---- min-distance matching (argmin first-wins) + kps compose ----
    for (int p = tid; p < 900; p += 256) {
        int j = p / 100, k = p - j * 100;
        float qx = kx[j][k], qy = ky[j][k];
        float best = INFINITY; int bi = 0;
        for (int m = 0; m < 100; ++m) {
            float dx = qx - hxv[j][m];
            float dy = qy - hyv[j][m];
            float d2 = __fadd_rn(__fmul_rn(dx, dx), __fmul_rn(dy, dy));
            float d = __fsqrt_rn(d2);
            if (d < best) { best = d; bi = m; }
        }
        float ss = hsv[j][bi], hx = hxv[j][bi], hy = hyv[j][bi];
        float l = la[k], t = ta[k], rr = ra[k], bb = ba2[k];
        float th = __fmul_rn(fmaxf(__fsub_rn(bb, t), __fsub_rn(rr, l)), 0.3f);
        bool invalid = (hx < l) | (hx > rr) | (hy < t) | (hy > bb) |
                       (ss < 0.1f) | (best > th);
        float ox = invalid ? kx[j][k] : hx;
        float oy = invalid ? ky[j][k] : hy;
        float* o = det + ((size_t)b * KTOP + k) * 45;
        o[5 + 2 * j] = ox * 4.0f;
        o[6 + 2 * j] = oy * 4.0f;
        o[26 + j]    = ss;
    }
}

// ---------------------------------------------------------------------------
extern "C" void kernel_launch(void* const* d_in, const int* in_sizes, int n_in,
                              void* d_out, int out_size, void* d_ws, size_t ws_size,
                              hipStream_t stream) {
    const float* hm    = (const float*)d_in[0];
    const float* wh    = (const float*)d_in[1];
    const float* hps   = (const float*)d_in[2];
    const float* dimp  = (const float*)d_in[3];
    const float* rot   = (const float*)d_in[4];
    const float* prob  = (const float*)d_in[5];
    const float* reg   = (const float*)d_in[6];
    const float* hm_hp = (const float*)d_in[7];
    const float* hpo   = (const float*)d_in[8];
    float* det = (float*)d_out;

    u32* tkKey = (u32*)d_ws;               // 192*100 u32
    u32* tkIdx = tkKey + NIMG * KTOP;      // 192*100 u32

    fused_nms_select_kernel<<<NIMG, NTHR, 0, stream>>>(hm, hm_hp, tkKey, tkIdx);
    decode_kernel<<<B_, 256, 0, stream>>>(tkKey, tkIdx, wh, hps, dimp, rot,
                                          prob, reg, hpo, det);
}

// Round 4
// 163.787 us; speedup vs baseline: 2.1431x; 1.1386x over previous
//
#include <hip/hip_runtime.h>
#include <math.h>

typedef unsigned int u32;
typedef unsigned short u16;
typedef unsigned long long u64;

#define HW    30720     // 96*320
#define W_    320
#define H_    96
#define B_    16
#define KTOP  100
#define NIMG  192       // 16*3 (hm) + 16*9 (hm_hp)
#define NTHR  1024
#define SCAP  4096      // survivor capacity (expected ~3460, ~11 sigma margin)

// ---------------------------------------------------------------------------
// Fused kernel: one block per (b,c) image, 1024 threads.
//  1. Stage full 96x320 image in LDS (float4 coalesced).
//  2. 3x3 NMS from LDS; survivors push (sigmoid-key u32, pix u16) directly.
//  3. One-round 12-bit radix histogram on key[31:20] + suffix scan -> cut bin
//     with >= 100 qualifiers (cut-bin population is tiny for this data).
//  4. Compact qualifiers as packed (key<<32)|~pix u64, then ONE-BARRIER
//     rank-select (exact lax.top_k order: value desc, idx asc; keys+~pix are
//     distinct per pixel so ranks are a permutation). Bitonic fallback for
//     q > 1024 (block-uniform branch).
// ---------------------------------------------------------------------------
__global__ __launch_bounds__(NTHR) void fused_nms_select_kernel(
    const float* __restrict__ hm, const float* __restrict__ hm_hp,
    u32* __restrict__ tkKey, u32* __restrict__ tkIdx)
{
    const int row = blockIdx.x;
    const int tid = threadIdx.x;

    __shared__ __align__(16) float img[HW];   // 120 KB; aliased post-NMS
    __shared__ u32 candKey[SCAP];             // 16 KB
    __shared__ u16 candPix[SCAP];             // 8 KB
    __shared__ u32 chunkv[256];
    __shared__ u32 selb1, cnt, cnt2;

    u32* hist  = (u32*)img;                   // [0..4095]   (16 KB, post-NMS)
    u64* cand2 = (u64*)(img + 4096);          // [4096..8191] floats (16 KB)

    if (tid == 0) { cnt = 0; cnt2 = 0; }

    // ---- phase 1: stage image ----
    const float4* src4 = (const float4*)((row < 48)
        ? (hm + (size_t)row * HW) : (hm_hp + (size_t)(row - 48) * HW));
    float4* img4 = (float4*)img;
    #pragma unroll
    for (int j = 0; j < 8; ++j) {
        int i = tid + j * NTHR;
        if (i < HW / 4) img4[i] = src4[i];
    }
    __syncthreads();

    // ---- phase 2: 3x3 NMS from LDS; survivors -> (key, pix) push ----
    for (int q = tid; q < HW / 4; q += NTHR) {
        int pix0 = q * 4;
        int y = pix0 / W_;
        int x0 = pix0 - y * W_;
        int ym = (y > 0 ? y - 1 : 0) * W_;
        int yc = y * W_;
        int yp = (y < H_ - 1 ? y + 1 : H_ - 1) * W_;
        float cm[6];
        #pragma unroll
        for (int c = 0; c < 6; ++c) {
            int xc = x0 - 1 + c;
            xc = (xc < 0) ? 0 : (xc > W_ - 1 ? W_ - 1 : xc);
            cm[c] = fmaxf(fmaxf(img[ym + xc], img[yc + xc]), img[yp + xc]);
        }
        #pragma unroll
        for (int j = 0; j < 4; ++j) {
            float cen = img[yc + x0 + j];
            float m = fmaxf(fmaxf(cm[j], cm[j + 1]), cm[j + 2]);
            if (cen == m) {
                float s = 1.0f / (1.0f + expf(-cen));   // same expr as validated
                u32 p = atomicAdd(&cnt, 1u);
                if (p < SCAP) {
                    candKey[p] = __float_as_uint(s);
                    candPix[p] = (u16)(pix0 + j);
                }
            }
        }
    }
    __syncthreads();                          // img free after this point
    const u32 n = (cnt > SCAP) ? SCAP : cnt;

    // ---- phase 3: one-round histogram of key[31:20] ----
    #pragma unroll
    for (int j = 0; j < 4; ++j) hist[tid + j * NTHR] = 0;
    __syncthreads();
    for (u32 i = tid; i < n; i += NTHR)
        atomicAdd(&hist[candKey[i] >> 20], 1u);
    __syncthreads();
    if (tid < 256) {
        u32 s = 0; int c0 = tid * 16;
        #pragma unroll
        for (int q = 0; q < 16; ++q) s += hist[c0 + q];
        chunkv[tid] = s;
    }
    __syncthreads();
    // parallel suffix scan: chunkv[c] = sum_{j>=c} chunkv[j]
    for (int d = 1; d < 256; d <<= 1) {
        u32 t = 0;
        if (tid < 256 - d) t = chunkv[tid + d];
        __syncthreads();
        if (tid < 256) chunkv[tid] += t;
        __syncthreads();
    }
    if (tid < 256) {
        u32 Sc = chunkv[tid];
        u32 Sn = (tid == 255) ? 0u : chunkv[tid + 1];
        if (Sc >= KTOP && Sn < KTOP) {        // exactly one thread
            u32 run = Sn;
            for (int bin = tid * 16 + 15; bin >= tid * 16; --bin) {
                u32 h = hist[bin];
                if (run + h >= KTOP) { selb1 = (u32)bin; break; }
                run += h;
            }
        }
    }
    __syncthreads();
    const u32 b1 = selb1;

    // ---- phase 4: compact qualifiers (key[31:20] >= cut bin) ----
    for (u32 i = tid; i < n; i += NTHR) {
        u32 k = candKey[i];
        if ((k >> 20) >= b1) {
            u32 p = atomicAdd(&cnt2, 1u);
            if (p < 2048) cand2[p] = ((u64)k << 32) | (u32)(~(u32)candPix[i]);
        }
    }
    __syncthreads();
    u32 q = cnt2; if (q > 2048) q = 2048;

    if (q <= NTHR) {
        // ---- rank-select: one barrier already done; direct global write ----
        if (tid < q) {
            u64 v = cand2[tid];
            u32 rank = 0;
            for (u32 i = 0; i < q; ++i) rank += (cand2[i] > v);
            if (rank < KTOP) {
                tkKey[row * KTOP + rank] = (u32)(v >> 32);
                tkIdx[row * KTOP + rank] = ~(u32)v;
            }
        }
    } else {
        // ---- fallback: bitonic sort (block-uniform branch) ----
        u32 npow = 128; while (npow < q) npow <<= 1;
        for (u32 i = q + tid; i < npow; i += NTHR) cand2[i] = 0ull;
        __syncthreads();
        for (u32 ks = 2; ks <= npow; ks <<= 1) {
            for (u32 j = ks >> 1; j > 0; j >>= 1) {
                for (u32 i = tid; i < npow; i += NTHR) {
                    u32 ix = i ^ j;
                    if (ix > i) {
                        u64 a = cand2[i], b = cand2[ix];
                        bool sw = ((i & ks) == 0) ? (a < b) : (a > b);
                        if (sw) { cand2[i] = b; cand2[ix] = a; }
                    }
                }
                __syncthreads();
            }
        }
        if (tid < KTOP) {
            u64 v = cand2[tid];
            tkKey[row * KTOP + tid] = (u32)(v >> 32);
            tkIdx[row * KTOP + tid] = ~(u32)v;
        }
    }
}

// ---------------------------------------------------------------------------
// Decode kernel v2: one block per (b, j) pair -> 144 blocks, 320 threads.
// Stage-2 top-100-of-300 via one-barrier rank-select (identical ordering to
// the validated bitonic: packed (key<<32)|~(c*100+r), distinct). Thread
// groups: [0,100) detection gathers + matching; [100,200) hm_hp prep;
// [200,300) (j==0 only) dim/rot/prob fields. All det fields disjoint per j.
// ---------------------------------------------------------------------------
__global__ __launch_bounds__(320) void decode_kernel(
    const u32* __restrict__ tkKey, const u32* __restrict__ tkIdx,
    const float* __restrict__ wh,   const float* __restrict__ hps,
    const float* __restrict__ dimp, const float* __restrict__ rot,
    const float* __restrict__ prob, const float* __restrict__ reg,
    const float* __restrict__ hpo,  float* __restrict__ det)
{
    const int blk = blockIdx.x;
    const int b = blk / 9;
    const int j = blk - b * 9;
    const int tid = threadIdx.x;

    __shared__ u64 arr[300];
    __shared__ u64 selv[KTOP];
    __shared__ float hsv[KTOP], hxv[KTOP], hyv[KTOP];

    // ---- stage-2 candidate load ----
    if (tid < 300) {
        int c = tid / 100, r = tid - c * 100;
        u32 key = tkKey[(b * 3 + c) * KTOP + r];
        arr[tid] = ((u64)key << 32) | (u32)(~(u32)tid);   // tid == c*K + r
    }
    __syncthreads();
    // ---- rank-select top-100 of 300 ----
    if (tid < 300) {
        u64 v = arr[tid];
        u32 rank = 0;
        for (int i = 0; i < 300; ++i) rank += (arr[i] > v);
        if (rank < KTOP) selv[rank] = v;
    }
    __syncthreads();

    // registers carried from gather phase to matching phase (threads 0..99)
    float l = 0.f, t = 0.f, rr = 0.f, bb = 0.f, kxr = 0.f, kyr = 0.f;

    if (tid < KTOP) {
        // ---- detection gathers ----
        int k = tid;
        u64 v = selv[k];
        u32 pos = ~(u32)v;
        if (pos > 299u) pos = 299u;
        u32 key = (u32)(v >> 32);
        int c = (int)pos / 100, r = (int)pos - c * 100;
        u32 sid = tkIdx[(b * 3 + c) * KTOP + r];
        if (sid > HW - 1) sid = HW - 1;
        float score = __uint_as_float(key);
        int yy = (int)sid / W_, xx = (int)sid - yy * W_;
        float xs0 = (float)xx, ys0 = (float)yy;
        float r0 = reg[((size_t)b * 2 + 0) * HW + sid];
        float r1 = reg[((size_t)b * 2 + 1) * HW + sid];
        float xsv = xs0 + r0, ysv = ys0 + r1;
        float w0 = wh[((size_t)b * 2 + 0) * HW + sid];
        float w1 = wh[((size_t)b * 2 + 1) * HW + sid];
        l  = xsv - w0 * 0.5f;
        t  = ysv - w1 * 0.5f;
        rr = xsv + w0 * 0.5f;
        bb = ysv + w1 * 0.5f;
        kxr = hps[((size_t)b * 18 + 2 * j)     * HW + sid] + xs0;
        kyr = hps[((size_t)b * 18 + 2 * j + 1) * HW + sid] + ys0;
        if (j == 0) {
            float* o = det + ((size_t)b * KTOP + k) * 45;
            o[0] = l * 4.0f; o[1] = t * 4.0f; o[2] = rr * 4.0f; o[3] = bb * 4.0f;
            o[4] = score;
            o[44] = (float)c;
        }
    } else if (tid < 200) {
        // ---- hm_hp candidate prep for (b, j) ----
        int r = tid - 100;
        int rw = 48 + b * 9 + j;
        u32 key = tkKey[rw * KTOP + r];
        u32 idx = tkIdx[rw * KTOP + r];
        if (idx > HW - 1) idx = HW - 1;
        float s = __uint_as_float(key);
        int yy = (int)idx / W_, xx = (int)idx - yy * W_;
        float hx = (float)xx + hpo[((size_t)b * 2 + 0) * HW + idx];
        float hy = (float)yy + hpo[((size_t)b * 2 + 1) * HW + idx];
        bool valid = s > 0.1f;
        hsv[r] = valid ? s : -1.0f;
        hxv[r] = valid ? hx : -10000.0f;
        hyv[r] = valid ? hy : -10000.0f;
    } else if (tid < 300 && j == 0) {
        // ---- j-invariant per-detection fields (dim/rot/prob) ----
        int k = tid - 200;
        u64 v = selv[k];
        u32 pos = ~(u32)v;
        if (pos > 299u) pos = 299u;
        int c = (int)pos / 100, r = (int)pos - c * 100;
        u32 sid = tkIdx[(b * 3 + c) * KTOP + r];
        if (sid > HW - 1) sid = HW - 1;
        float* o = det + ((size_t)b * KTOP + k) * 45;
        #pragma unroll
        for (int qq = 0; qq < 3; ++qq)
            o[23 + qq] = dimp[((size_t)b * 3 + qq) * HW + sid];
        #pragma unroll
        for (int qq = 0; qq < 8; ++qq)
            o[35 + qq] = rot[((size_t)b * 8 + qq) * HW + sid];
        o[43] = prob[(size_t)b * HW + sid];
    }
    __syncthreads();

    // ---- min-distance matching (argmin first-wins) + kps compose ----
    if (tid < KTOP) {
        int k = tid;
        float best = INFINITY; int bi = 0;
        for (int m = 0; m < 100; ++m) {
            float dx = kxr - hxv[m];
            float dy = kyr - hyv[m];
            float d2 = __fadd_rn(__fmul_rn(dx, dx), __fmul_rn(dy, dy));
            float d = __fsqrt_rn(d2);
            if (d < best) { best = d; bi = m; }
        }
        float ss = hsv[bi], hx = hxv[bi], hy = hyv[bi];
        float th = __fmul_rn(fmaxf(__fsub_rn(bb, t), __fsub_rn(rr, l)), 0.3f);
        bool invalid = (hx < l) | (hx > rr) | (hy < t) | (hy > bb) |
                       (ss < 0.1f) | (best > th);
        float ox = invalid ? kxr : hx;
        float oy = invalid ? kyr : hy;
        float* o = det + ((size_t)b * KTOP + k) * 45;
        o[5 + 2 * j] = ox * 4.0f;
        o[6 + 2 * j] = oy * 4.0f;
        o[26 + j]    = ss;
    }
}

// ---------------------------------------------------------------------------
extern "C" void kernel_launch(void* const* d_in, const int* in_sizes, int n_in,
                              void* d_out, int out_size, void* d_ws, size_t ws_size,
                              hipStream_t stream) {
    const float* hm    = (const float*)d_in[0];
    const float* wh    = (const float*)d_in[1];
    const float* hps   = (const float*)d_in[2];
    const float* dimp  = (const float*)d_in[3];
    const float* rot   = (const float*)d_in[4];
    const float* prob  = (const float*)d_in[5];
    const float* reg   = (const float*)d_in[6];
    const float* hm_hp = (const float*)d_in[7];
    const float* hpo   = (const float*)d_in[8];
    float* det = (float*)d_out;

    u32* tkKey = (u32*)d_ws;               // 192*100 u32
    u32* tkIdx = tkKey + NIMG * KTOP;      // 192*100 u32

    fused_nms_select_kernel<<<NIMG, NTHR, 0, stream>>>(hm, hm_hp, tkKey, tkIdx);
    decode_kernel<<<B_ * 9, 320, 0, stream>>>(tkKey, tkIdx, wh, hps, dimp, rot,
                                              prob, reg, hpo, det);
}

// Round 5
// 156.559 us; speedup vs baseline: 2.2420x; 1.0462x over previous
//
#include <hip/hip_runtime.h>
#include <math.h>

typedef unsigned int u32;
typedef unsigned short u16;
typedef unsigned long long u64;

#define HW    30720     // 96*320
#define W_    320
#define H_    96
#define B_    16
#define KTOP  100
#define NIMG  192       // 16*3 (hm) + 16*9 (hm_hp)
#define NTHR  1024
#define SCAP  4096      // survivor capacity (expected ~3413, ~12 sigma margin)

// ---------------------------------------------------------------------------
// Fused kernel v3: one block per (b,c) image, 1024 threads, NO image staging.
//  NMS reads straight from global: per 4-pixel quad, 3 aligned float4 row
//  loads + up to 6 edge scalars (all lane-contiguous, stride 16 B -> fully
//  coalesced; rows re-read 3x but served by L1/L2). Column max in registers.
//  Survivors -> (sigmoid-key u32, pix u16) pushed to LDS.
//  Selection: two-round 12-bit radix cut (key[31:20], then key[19:8]) with
//  single-wave shuffle suffix-scan (no barriers), compact qualifiers
//  (q ~ 100-130), one-barrier rank-select (exact lax.top_k order: value
//  desc, idx asc; packed keys distinct). Bitonic fallback for q > 1024.
// ---------------------------------------------------------------------------
__global__ __launch_bounds__(NTHR) void fused_nms_select_kernel(
    const float* __restrict__ hm, const float* __restrict__ hm_hp,
    u32* __restrict__ tkKey, u32* __restrict__ tkIdx)
{
    const int row = blockIdx.x;
    const int tid = threadIdx.x;

    __shared__ u32 candKey[SCAP];             // 16 KB
    __shared__ u16 candPix[SCAP];             // 8 KB
    __shared__ u32 hist[4096];                // 16 KB; aliased by cand2 later
    __shared__ u32 selb1, selG1, selb2;
    __shared__ u32 cnt, cnt2;

    u64* cand2 = (u64*)hist;                  // 2048 u64, alias after round 2

    if (tid == 0) { cnt = 0; cnt2 = 0; }
    #pragma unroll
    for (int j = 0; j < 4; ++j) hist[tid + j * NTHR] = 0;

    const float* __restrict__ base = (row < 48)
        ? (hm + (size_t)row * HW) : (hm_hp + (size_t)(row - 48) * HW);
    __syncthreads();                                            // B1

    // ---- NMS from global, one 4-pixel quad per thread-iteration ----
    for (int q = tid; q < HW / 4; q += NTHR) {
        int y  = q / 80;            // 80 quads per row
        int qx = q - y * 80;
        int x0 = qx * 4;
        const float* rm = base + (y > 0 ? y - 1 : 0) * W_;
        const float* rc = base + y * W_;
        const float* rp = base + (y < H_ - 1 ? y + 1 : H_ - 1) * W_;
        float4 am = *(const float4*)(rm + x0);
        float4 ac = *(const float4*)(rc + x0);
        float4 ap = *(const float4*)(rp + x0);
        // column maxes of the quad
        float cm0 = fmaxf(fmaxf(am.x, ac.x), ap.x);
        float cm1 = fmaxf(fmaxf(am.y, ac.y), ap.y);
        float cm2 = fmaxf(fmaxf(am.z, ac.z), ap.z);
        float cm3 = fmaxf(fmaxf(am.w, ac.w), ap.w);
        // edge column maxes (clamped at image borders)
        float cl, cr;
        if (qx > 0)
            cl = fmaxf(fmaxf(rm[x0 - 1], rc[x0 - 1]), rp[x0 - 1]);
        else cl = cm0;
        if (qx < 79)
            cr = fmaxf(fmaxf(rm[x0 + 4], rc[x0 + 4]), rp[x0 + 4]);
        else cr = cm3;

        float cen[4] = {ac.x, ac.y, ac.z, ac.w};
        float mx[4];
        mx[0] = fmaxf(fmaxf(cl,  cm0), cm1);
        mx[1] = fmaxf(fmaxf(cm0, cm1), cm2);
        mx[2] = fmaxf(fmaxf(cm1, cm2), cm3);
        mx[3] = fmaxf(fmaxf(cm2, cm3), cr);
        #pragma unroll
        for (int j = 0; j < 4; ++j) {
            if (cen[j] == mx[j]) {
                float s = 1.0f / (1.0f + expf(-cen[j]));  // same expr as validated
                u32 p = atomicAdd(&cnt, 1u);
                if (p < SCAP) {
                    candKey[p] = __float_as_uint(s);
                    candPix[p] = (u16)(x0 + j + y * W_);
                }
            }
        }
    }
    __syncthreads();                                            // B2
    const u32 n = (cnt > SCAP) ? SCAP : cnt;

    // ---- round 1: histogram key[31:20] ----
    for (u32 i = tid; i < n; i += NTHR)
        atomicAdd(&hist[candKey[i] >> 20], 1u);
    __syncthreads();                                            // B3
    // single-wave suffix scan + cut-bin find (no barriers inside)
    if (tid < 64) {
        int lane = tid;
        u32 v[4], t[4];
        #pragma unroll
        for (int k = 0; k < 4; ++k) {
            u32 s = 0; int b0 = (lane * 4 + k) * 16;
            #pragma unroll
            for (int qq = 0; qq < 16; ++qq) s += hist[b0 + qq];
            v[k] = s;
        }
        t[3] = v[3]; t[2] = v[2] + t[3]; t[1] = v[1] + t[2]; t[0] = v[0] + t[1];
        u32 lt = t[0], s = lt;
        #pragma unroll
        for (int d = 1; d < 64; d <<= 1) {
            u32 o = __shfl_down(s, d);
            if (lane + d < 64) s += o;
        }
        u32 SH = s - lt;    // suffix over chunks owned by lanes > lane
        u32 sfx[5] = {t[0] + SH, t[1] + SH, t[2] + SH, t[3] + SH, SH};
        #pragma unroll
        for (int k = 0; k < 4; ++k) {
            if (sfx[k] >= KTOP && sfx[k + 1] < KTOP) {
                u32 run = sfx[k + 1];
                int c = lane * 4 + k;
                for (int bin = c * 16 + 15; bin >= c * 16; --bin) {
                    u32 h = hist[bin];
                    if (run + h >= KTOP) { selb1 = (u32)bin; selG1 = run; break; }
                    run += h;
                }
            }
        }
    }
    __syncthreads();                                            // B4
    const u32 b1 = selb1, G1 = selG1;

    // ---- round 2: histogram key[19:8] within bin b1 ----
    #pragma unroll
    for (int j = 0; j < 4; ++j) hist[tid + j * NTHR] = 0;
    __syncthreads();                                            // B5
    for (u32 i = tid; i < n; i += NTHR) {
        u32 k = candKey[i];
        if ((k >> 20) == b1) atomicAdd(&hist[(k >> 8) & 0xFFFu], 1u);
    }
    __syncthreads();                                            // B6
    {
        const u32 K2 = KTOP - G1;                 // >= 1
        if (tid < 64) {
            int lane = tid;
            u32 v[4], t[4];
            #pragma unroll
            for (int k = 0; k < 4; ++k) {
                u32 s = 0; int b0 = (lane * 4 + k) * 16;
                #pragma unroll
                for (int qq = 0; qq < 16; ++qq) s += hist[b0 + qq];
                v[k] = s;
            }
            t[3] = v[3]; t[2] = v[2] + t[3]; t[1] = v[1] + t[2]; t[0] = v[0] + t[1];
            u32 lt = t[0], s = lt;
            #pragma unroll
            for (int d = 1; d < 64; d <<= 1) {
                u32 o = __shfl_down(s, d);
                if (lane + d < 64) s += o;
            }
            u32 SH = s - lt;
            u32 sfx[5] = {t[0] + SH, t[1] + SH, t[2] + SH, t[3] + SH, SH};
            #pragma unroll
            for (int k = 0; k < 4; ++k) {
                if (sfx[k] >= K2 && sfx[k + 1] < K2) {
                    u32 run = sfx[k + 1];
                    int c = lane * 4 + k;
                    for (int bin = c * 16 + 15; bin >= c * 16; --bin) {
                        u32 h = hist[bin];
                        if (run + h >= K2) { selb2 = (u32)bin; break; }
                        run += h;
                    }
                }
            }
        }
    }
    __syncthreads();                                            // B7 (hist free after)
    const u32 cut24 = (b1 << 12) | selb2;

    // ---- compact qualifiers (key[31:8] >= cut24) into cand2 (aliases hist) ----
    for (u32 i = tid; i < n; i += NTHR) {
        u32 k = candKey[i];
        if ((k >> 8) >= cut24) {
            u32 p = atomicAdd(&cnt2, 1u);
            if (p < 2048) cand2[p] = ((u64)k << 32) | (u32)(~(u32)candPix[i]);
        }
    }
    __syncthreads();                                            // B8
    u32 q = cnt2; if (q > 2048) q = 2048;

    if (q <= NTHR) {
        // ---- rank-select, direct global write ----
        if (tid < q) {
            u64 v = cand2[tid];
            u32 rank = 0;
            for (u32 i = 0; i < q; ++i) rank += (cand2[i] > v);
            if (rank < KTOP) {
                tkKey[row * KTOP + rank] = (u32)(v >> 32);
                tkIdx[row * KTOP + rank] = ~(u32)v;
            }
        }
    } else {
        // ---- fallback: bitonic sort (block-uniform branch) ----
        u32 npow = 128; while (npow < q) npow <<= 1;
        for (u32 i = q + tid; i < npow; i += NTHR) cand2[i] = 0ull;
        __syncthreads();
        for (u32 ks = 2; ks <= npow; ks <<= 1) {
            for (u32 j = ks >> 1; j > 0; j >>= 1) {
                for (u32 i = tid; i < npow; i += NTHR) {
                    u32 ix = i ^ j;
                    if (ix > i) {
                        u64 a = cand2[i], b = cand2[ix];
                        bool sw = ((i & ks) == 0) ? (a < b) : (a > b);
                        if (sw) { cand2[i] = b; cand2[ix] = a; }
                    }
                }
                __syncthreads();
            }
        }
        if (tid < KTOP) {
            u64 v = cand2[tid];
            tkKey[row * KTOP + tid] = (u32)(v >> 32);
            tkIdx[row * KTOP + tid] = ~(u32)v;
        }
    }
}

// ---------------------------------------------------------------------------
// Decode kernel (unchanged from validated round-4 version).
// ---------------------------------------------------------------------------
__global__ __launch_bounds__(320) void decode_kernel(
    const u32* __restrict__ tkKey, const u32* __restrict__ tkIdx,
    const float* __restrict__ wh,   const float* __restrict__ hps,
    const float* __restrict__ dimp, const float* __restrict__ rot,
    const float* __restrict__ prob, const float* __restrict__ reg,
    const float* __restrict__ hpo,  float* __restrict__ det)
{
    const int blk = blockIdx.x;
    const int b = blk / 9;
    const int j = blk - b * 9;
    const int tid = threadIdx.x;

    __shared__ u64 arr[300];
    __shared__ u64 selv[KTOP];
    __shared__ float hsv[KTOP], hxv[KTOP], hyv[KTOP];

    if (tid < 300) {
        int c = tid / 100, r = tid - c * 100;
        u32 key = tkKey[(b * 3 + c) * KTOP + r];
        arr[tid] = ((u64)key << 32) | (u32)(~(u32)tid);   // tid == c*K + r
    }
    __syncthreads();
    if (tid < 300) {
        u64 v = arr[tid];
        u32 rank = 0;
        for (int i = 0; i < 300; ++i) rank += (arr[i] > v);
        if (rank < KTOP) selv[rank] = v;
    }
    __syncthreads();

    float l = 0.f, t = 0.f, rr = 0.f, bb = 0.f, kxr = 0.f, kyr = 0.f;

    if (tid < KTOP) {
        int k = tid;
        u64 v = selv[k];
        u32 pos = ~(u32)v;
        if (pos > 299u) pos = 299u;
        u32 key = (u32)(v >> 32);
        int c = (int)pos / 100, r = (int)pos - c * 100;
        u32 sid = tkIdx[(b * 3 + c) * KTOP + r];
        if (sid > HW - 1) sid = HW - 1;
        float score = __uint_as_float(key);
        int yy = (int)sid / W_, xx = (int)sid - yy * W_;
        float xs0 = (float)xx, ys0 = (float)yy;
        float r0 = reg[((size_t)b * 2 + 0) * HW + sid];
        float r1 = reg[((size_t)b * 2 + 1) * HW + sid];
        float xsv = xs0 + r0, ysv = ys0 + r1;
        float w0 = wh[((size_t)b * 2 + 0) * HW + sid];
        float w1 = wh[((size_t)b * 2 + 1) * HW + sid];
        l  = xsv - w0 * 0.5f;
        t  = ysv - w1 * 0.5f;
        rr = xsv + w0 * 0.5f;
        bb = ysv + w1 * 0.5f;
        kxr = hps[((size_t)b * 18 + 2 * j)     * HW + sid] + xs0;
        kyr = hps[((size_t)b * 18 + 2 * j + 1) * HW + sid] + ys0;
        if (j == 0) {
            float* o = det + ((size_t)b * KTOP + k) * 45;
            o[0] = l * 4.0f; o[1] = t * 4.0f; o[2] = rr * 4.0f; o[3] = bb * 4.0f;
            o[4] = score;
            o[44] = (float)c;
        }
    } else if (tid < 200) {
        int r = tid - 100;
        int rw = 48 + b * 9 + j;
        u32 key = tkKey[rw * KTOP + r];
        u32 idx = tkIdx[rw * KTOP + r];
        if (idx > HW - 1) idx = HW - 1;
        float s = __uint_as_float(key);
        int yy = (int)idx / W_, xx = (int)idx - yy * W_;
        float hx = (float)xx + hpo[((size_t)b * 2 + 0) * HW + idx];
        float hy = (float)yy + hpo[((size_t)b * 2 + 1) * HW + idx];
        bool valid = s > 0.1f;
        hsv[r] = valid ? s : -1.0f;
        hxv[r] = valid ? hx : -10000.0f;
        hyv[r] = valid ? hy : -10000.0f;
    } else if (tid < 300 && j == 0) {
        int k = tid - 200;
        u64 v = selv[k];
        u32 pos = ~(u32)v;
        if (pos > 299u) pos = 299u;
        int c = (int)pos / 100, r = (int)pos - c * 100;
        u32 sid = tkIdx[(b * 3 + c) * KTOP + r];
        if (sid > HW - 1) sid = HW - 1;
        float* o = det + ((size_t)b * KTOP + k) * 45;
        #pragma unroll
        for (int qq = 0; qq < 3; ++qq)
            o[23 + qq] = dimp[((size_t)b * 3 + qq) * HW + sid];
        #pragma unroll
        for (int qq = 0; qq < 8; ++qq)
            o[35 + qq] = rot[((size_t)b * 8 + qq) * HW + sid];
        o[43] = prob[(size_t)b * HW + sid];
    }
    __syncthreads();

    if (tid < KTOP) {
        int k = tid;
        float best = INFINITY; int bi = 0;
        for (int m = 0; m < 100; ++m) {
            float dx = kxr - hxv[m];
            float dy = kyr - hyv[m];
            float d2 = __fadd_rn(__fmul_rn(dx, dx), __fmul_rn(dy, dy));
            float d = __fsqrt_rn(d2);
            if (d < best) { best = d; bi = m; }
        }
        float ss = hsv[bi], hx = hxv[bi], hy = hyv[bi];
        float th = __fmul_rn(fmaxf(__fsub_rn(bb, t), __fsub_rn(rr, l)), 0.3f);
        bool invalid = (hx < l) | (hx > rr) | (hy < t) | (hy > bb) |
                       (ss < 0.1f) | (best > th);
        float ox = invalid ? kxr : hx;
        float oy = invalid ? kyr : hy;
        float* o = det + ((size_t)b * KTOP + k) * 45;
        o[5 + 2 * j] = ox * 4.0f;
        o[6 + 2 * j] = oy * 4.0f;
        o[26 + j]    = ss;
    }
}

// ---------------------------------------------------------------------------
extern "C" void kernel_launch(void* const* d_in, const int* in_sizes, int n_in,
                              void* d_out, int out_size, void* d_ws, size_t ws_size,
                              hipStream_t stream) {
    const float* hm    = (const float*)d_in[0];
    const float* wh    = (const float*)d_in[1];
    const float* hps   = (const float*)d_in[2];
    const float* dimp  = (const float*)d_in[3];
    const float* rot   = (const float*)d_in[4];
    const float* prob  = (const float*)d_in[5];
    const float* reg   = (const float*)d_in[6];
    const float* hm_hp = (const float*)d_in[7];
    const float* hpo   = (const float*)d_in[8];
    float* det = (float*)d_out;

    u32* tkKey = (u32*)d_ws;               // 192*100 u32
    u32* tkIdx = tkKey + NIMG * KTOP;      // 192*100 u32

    fused_nms_select_kernel<<<NIMG, NTHR, 0, stream>>>(hm, hm_hp, tkKey, tkIdx);
    decode_kernel<<<B_ * 9, 320, 0, stream>>>(tkKey, tkIdx, wh, hps, dimp, rot,
                                              prob, reg, hpo, det);
}